// Round 18
// baseline (421.712 us; speedup 1.0000x reference)
//
#include <hip/hip_runtime.h>
#include <math.h>

#define N_NODES 20000
#define E0      320000
#define E_TOT   (E0 + N_NODES)   /* 340000: edges + self-loops */
#define N_GRAPHS 64
#define IN_DIM  39
#define HID     128
#define HEADS   4
#define HHID    (HEADS * HID)    /* 512 */
#define NUM_CONV 3
#define PRED_HID 32
#define NEG_SLOPE 0.2f

__device__ __forceinline__ int esrc(const int* __restrict__ ei, int e) {
    return e < E0 ? ei[e] : (e - E0);
}
__device__ __forceinline__ int edst(const int* __restrict__ ei, int e) {
    return e < E0 ? ei[E0 + e] : (e - E0);
}

// async global->LDS, 16B per lane; lds pointer must be wave-uniform base
__device__ __forceinline__ void gload_lds16(const void* g, void* l) {
    __builtin_amdgcn_global_load_lds(
        (const __attribute__((address_space(1))) void*)g,
        (__attribute__((address_space(3))) void*)l, 16, 0, 0);
}

// ---------------- fused: degree histogram + Wsd precompute ----------------
__global__ void k_degwsd(const int* __restrict__ ei, int* __restrict__ deg,
                         const float* __restrict__ lin_W, const float* __restrict__ attS,
                         const float* __restrict__ attD, float* __restrict__ Wsd) {
    int e = blockIdx.x * blockDim.x + threadIdx.x;
    if (e < E_TOT) atomicAdd(&deg[edst(ei, e)], 1);
    if (blockIdx.x < NUM_CONV * 8 && threadIdx.x < HID) {
        int l = blockIdx.x >> 3, j = blockIdx.x & 7, h = j & 3, k = threadIdx.x;
        const float* wr = lin_W + (size_t)l * HID * HHID + (size_t)k * HHID + h * HID;
        const float* av = ((j < 4) ? attS : attD) + ((size_t)l * HEADS + h) * HID;
        float dot = 0.f;
#pragma unroll 4
        for (int f = 0; f < HID; f++) dot += wr[f] * av[f];
        Wsd[(size_t)l * 8 * HID + j * HID + k] = dot;
    }
}

__global__ __launch_bounds__(1024) void k_scan(const int* __restrict__ deg,
                                               int* __restrict__ row_ptr,
                                               int* __restrict__ cursor) {
    __shared__ int part[1024];
    const int CHUNK = 20;
    int t = threadIdx.x;
    int base = t * CHUNK;
    int s = 0;
    for (int i = 0; i < CHUNK; i++) {
        int idx = base + i;
        if (idx < N_NODES) s += deg[idx];
    }
    part[t] = s;
    __syncthreads();
    for (int off = 1; off < 1024; off <<= 1) {
        int v = (t >= off) ? part[t - off] : 0;
        __syncthreads();
        part[t] += v;
        __syncthreads();
    }
    int run = part[t] - s;
    for (int i = 0; i < CHUNK; i++) {
        int idx = base + i;
        if (idx < N_NODES) {
            row_ptr[idx] = run;
            cursor[idx]  = run;
            run += deg[idx];
        }
    }
    if (t == 1023) row_ptr[N_NODES] = part[1023];
}

__global__ void k_scatter(const int* __restrict__ ei, int* __restrict__ cursor,
                          int* __restrict__ csr_src) {
    int e = blockIdx.x * blockDim.x + threadIdx.x;
    if (e >= E_TOT) return;
    int d = edst(ei, e);
    int pos = atomicAdd(&cursor[d], 1);
    csr_src[pos] = esrc(ei, e);
}

// ---------------- fused: embedding + layer-0 attention projection + g_sum zeroing ----------------
__global__ __launch_bounds__(256) void k_embproj(const float* __restrict__ nf,
                                                 const float* __restrict__ emb_W,
                                                 const float* __restrict__ emb_b,
                                                 const float* __restrict__ Wsd0,
                                                 float* __restrict__ x,
                                                 float* __restrict__ A8,
                                                 float* __restrict__ g_sum,
                                                 int* __restrict__ g_cnt) {
    if (blockIdx.x < 32) g_sum[blockIdx.x * 256 + threadIdx.x] = 0.f;
    if (blockIdx.x == 32 && threadIdx.x < N_GRAPHS) g_cnt[threadIdx.x] = 0;

    __shared__ float fsh[4 * 40];
    int wid = threadIdx.x >> 6, lane = threadIdx.x & 63;
    int n = blockIdx.x * 4 + wid;
    if (n >= N_NODES) return;
    if (lane < IN_DIM) fsh[wid * 40 + lane] = nf[(size_t)n * IN_DIM + lane];
    __syncthreads();
    float2 acc = *(const float2*)(emb_b + lane * 2);
#pragma unroll
    for (int k = 0; k < IN_DIM; k++) {
        float f = fsh[wid * 40 + k];
        float2 w = *(const float2*)(emb_W + k * HID + lane * 2);
        acc.x += f * w.x; acc.y += f * w.y;
    }
    *(float2*)(x + (size_t)n * HID + lane * 2) = acc;
    float p[8];
#pragma unroll
    for (int j = 0; j < 8; j++) {
        float2 w = *(const float2*)(Wsd0 + j * HID + lane * 2);
        float v = acc.x * w.x + acc.y * w.y;
#pragma unroll
        for (int off = 32; off; off >>= 1) v += __shfl_xor(v, off, 64);
        p[j] = v;
    }
    if (lane == 0) {
        *(float4*)(A8 + (size_t)n * 8)     = make_float4(p[0], p[1], p[2], p[3]);
        *(float4*)(A8 + (size_t)n * 8 + 4) = make_float4(p[4], p[5], p[6], p[7]);
    }
}

// ---------------- aggregation with fused lane-parallel edge softmax (R12) ----------------
__global__ __launch_bounds__(256) void k_aggr(const float* __restrict__ x,
                                              const int* __restrict__ row_ptr,
                                              const int* __restrict__ csr_src,
                                              const float* __restrict__ A8,
                                              float* __restrict__ agg) {
    int wid = threadIdx.x >> 6, lane = threadIdx.x & 63;
    int n = blockIdx.x * 4 + wid;
    if (n >= N_NODES) return;
    float4 vd = *(const float4*)(A8 + (size_t)n * 8 + 4);
    int beg = row_ptr[n], end = row_ptr[n + 1];
    float a0x = 0.f, a0y = 0.f, a1x = 0.f, a1y = 0.f;
    float a2x = 0.f, a2y = 0.f, a3x = 0.f, a3y = 0.f;
    float d0 = 0.f, d1 = 0.f, d2 = 0.f, d3 = 0.f;
    size_t lo = (size_t)(lane * 2);
    int eu = lane >> 2, eh = lane & 3;
    float vdh = (eh == 0) ? vd.x : (eh == 1) ? vd.y : (eh == 2) ? vd.z : vd.w;
    int i = beg;
    for (; i + 4 <= end; i += 4) {
        int s0 = csr_src[i];
        int s1 = csr_src[i + 1];
        int s2 = csr_src[i + 2];
        int s3 = csr_src[i + 3];
        float e = 0.f;
        if (lane < 16) {
            int su = (eu == 0) ? s0 : (eu == 1) ? s1 : (eu == 2) ? s2 : s3;
            float v = A8[(size_t)su * 8 + eh] + vdh;
            v = fmaxf(v, NEG_SLOPE * v);
            e = __expf(v);
        }
        float2 xv0 = *(const float2*)(x + (size_t)s0 * HID + lo);
        float2 xv1 = *(const float2*)(x + (size_t)s1 * HID + lo);
        float2 xv2 = *(const float2*)(x + (size_t)s2 * HID + lo);
        float2 xv3 = *(const float2*)(x + (size_t)s3 * HID + lo);
        float e00 = __shfl(e, 0, 64),  e01 = __shfl(e, 1, 64),  e02 = __shfl(e, 2, 64),  e03 = __shfl(e, 3, 64);
        float e10 = __shfl(e, 4, 64),  e11 = __shfl(e, 5, 64),  e12 = __shfl(e, 6, 64),  e13 = __shfl(e, 7, 64);
        float e20 = __shfl(e, 8, 64),  e21 = __shfl(e, 9, 64),  e22 = __shfl(e, 10, 64), e23 = __shfl(e, 11, 64);
        float e30 = __shfl(e, 12, 64), e31 = __shfl(e, 13, 64), e32 = __shfl(e, 14, 64), e33 = __shfl(e, 15, 64);
        a0x += e00 * xv0.x; a0y += e00 * xv0.y;
        a1x += e01 * xv0.x; a1y += e01 * xv0.y;
        a2x += e02 * xv0.x; a2y += e02 * xv0.y;
        a3x += e03 * xv0.x; a3y += e03 * xv0.y;
        d0 += e00; d1 += e01; d2 += e02; d3 += e03;
        a0x += e10 * xv1.x; a0y += e10 * xv1.y;
        a1x += e11 * xv1.x; a1y += e11 * xv1.y;
        a2x += e12 * xv1.x; a2y += e12 * xv1.y;
        a3x += e13 * xv1.x; a3y += e13 * xv1.y;
        d0 += e10; d1 += e11; d2 += e12; d3 += e13;
        a0x += e20 * xv2.x; a0y += e20 * xv2.y;
        a1x += e21 * xv2.x; a1y += e21 * xv2.y;
        a2x += e22 * xv2.x; a2y += e22 * xv2.y;
        a3x += e23 * xv2.x; a3y += e23 * xv2.y;
        d0 += e20; d1 += e21; d2 += e22; d3 += e23;
        a0x += e30 * xv3.x; a0y += e30 * xv3.y;
        a1x += e31 * xv3.x; a1y += e31 * xv3.y;
        a2x += e32 * xv3.x; a2y += e32 * xv3.y;
        a3x += e33 * xv3.x; a3y += e33 * xv3.y;
        d0 += e30; d1 += e31; d2 += e32; d3 += e33;
    }
    for (; i < end; i++) {
        int s0 = csr_src[i];
        float4 vs = *(const float4*)(A8 + (size_t)s0 * 8);
        float2 xv0 = *(const float2*)(x + (size_t)s0 * HID + lo);
        float v0 = vs.x + vd.x; v0 = fmaxf(v0, NEG_SLOPE * v0); float e0 = __expf(v0);
        float v1 = vs.y + vd.y; v1 = fmaxf(v1, NEG_SLOPE * v1); float e1 = __expf(v1);
        float v2 = vs.z + vd.z; v2 = fmaxf(v2, NEG_SLOPE * v2); float e2 = __expf(v2);
        float v3 = vs.w + vd.w; v3 = fmaxf(v3, NEG_SLOPE * v3); float e3 = __expf(v3);
        a0x += e0 * xv0.x; a0y += e0 * xv0.y;
        a1x += e1 * xv0.x; a1y += e1 * xv0.y;
        a2x += e2 * xv0.x; a2y += e2 * xv0.y;
        a3x += e3 * xv0.x; a3y += e3 * xv0.y;
        d0 += e0; d1 += e1; d2 += e2; d3 += e3;
    }
    float i0 = 1.f / d0, i1 = 1.f / d1, i2 = 1.f / d2, i3 = 1.f / d3;
    float* ag = agg + (size_t)n * HHID;
    *(float2*)(ag + 0 * HID + lo) = make_float2(a0x * i0, a0y * i0);
    *(float2*)(ag + 1 * HID + lo) = make_float2(a1x * i1, a1y * i1);
    *(float2*)(ag + 2 * HID + lo) = make_float2(a2x * i2, a2y * i2);
    *(float2*)(ag + 3 * HID + lo) = make_float2(a3x * i3, a3y * i3);
}

// ---------------- GEMM2 split-K: 512 threads, BM=128, 4x8 micro-tile ----------------
#define G2_BM 128
#define G2_KSPLIT 4
__global__ __launch_bounds__(512, 4) void k_gemm2(const float* __restrict__ agg,
                                                  const float* __restrict__ W,   // [128][512]
                                                  float* __restrict__ part, int M) {
    __shared__ float At[64][G2_BM];   // 32 KB, transposed + XOR-swizzled
    __shared__ float Bs[64 * HID];    // 32 KB, flat linear
    int tid = threadIdx.x;
    int row0 = blockIdx.x * G2_BM;
    int ks = blockIdx.y;
    int ty = tid >> 4, tx = tid & 15;   // ty 0..31, tx 0..15
    int r0 = ty * 4, c0 = tx * 4;
    float acc[4][8] = {};

#pragma unroll
    for (int kt = 0; kt < 2; kt++) {
        int kbase = ks * 128 + kt * 64;
        __syncthreads();
        // B tile via async global->LDS (linear dest: byte offset = idx*16)
#pragma unroll
        for (int i = 0; i < 4; i++) {
            int idx = tid + i * 512;
            int kr = idx >> 5;       // 0..63
            int c4 = idx & 31;
            int kg = kbase + kr;
            int hd = kg >> 7, kk = kg & 127;
            const float* src = W + (size_t)kk * HHID + hd * HID + c4 * 4;
            float* ldst = Bs + ((tid & ~63) + i * 512) * 4;   // wave-uniform base
            gload_lds16(src, ldst);
        }
        // A tile: 128 rows x 64 k -> transposed + swizzled (VGPR path)
#pragma unroll
        for (int i = 0; i < 4; i++) {
            int idx = tid + i * 512;
            int r = idx >> 4;        // 0..127
            int c4 = idx & 15;
            int gr = row0 + r;
            float4 v = make_float4(0.f, 0.f, 0.f, 0.f);
            if (gr < M) v = *(const float4*)(agg + (size_t)gr * HHID + kbase + c4 * 4);
            int sw = ((((r >> 2) ^ c4) & 31) << 2) + (r & 3);
            At[c4 * 4 + 0][sw] = v.x;
            At[c4 * 4 + 1][sw] = v.y;
            At[c4 * 4 + 2][sw] = v.z;
            At[c4 * 4 + 3][sw] = v.w;
        }
        __syncthreads();
#pragma unroll 4
        for (int k = 0; k < 64; k++) {
            float4 av = *(float4*)(&At[k][(((ty ^ (k >> 2)) & 31) << 2)]);
            float4 b1 = *(float4*)(&Bs[k * HID + c0]);
            float4 b2 = *(float4*)(&Bs[k * HID + c0 + 64]);
            acc[0][0] += av.x * b1.x; acc[0][1] += av.x * b1.y; acc[0][2] += av.x * b1.z; acc[0][3] += av.x * b1.w;
            acc[0][4] += av.x * b2.x; acc[0][5] += av.x * b2.y; acc[0][6] += av.x * b2.z; acc[0][7] += av.x * b2.w;
            acc[1][0] += av.y * b1.x; acc[1][1] += av.y * b1.y; acc[1][2] += av.y * b1.z; acc[1][3] += av.y * b1.w;
            acc[1][4] += av.y * b2.x; acc[1][5] += av.y * b2.y; acc[1][6] += av.y * b2.z; acc[1][7] += av.y * b2.w;
            acc[2][0] += av.z * b1.x; acc[2][1] += av.z * b1.y; acc[2][2] += av.z * b1.z; acc[2][3] += av.z * b1.w;
            acc[2][4] += av.z * b2.x; acc[2][5] += av.z * b2.y; acc[2][6] += av.z * b2.z; acc[2][7] += av.z * b2.w;
            acc[3][0] += av.w * b1.x; acc[3][1] += av.w * b1.y; acc[3][2] += av.w * b1.z; acc[3][3] += av.w * b1.w;
            acc[3][4] += av.w * b2.x; acc[3][5] += av.w * b2.y; acc[3][6] += av.w * b2.z; acc[3][7] += av.w * b2.w;
        }
    }
    float* pb = part + (size_t)ks * M * HID;
#pragma unroll
    for (int i = 0; i < 4; i++) {
        int gr = row0 + r0 + i;
        if (gr < M) {
            *(float4*)(pb + (size_t)gr * HID + c0) =
                make_float4(acc[i][0], acc[i][1], acc[i][2], acc[i][3]);
            *(float4*)(pb + (size_t)gr * HID + c0 + 64) =
                make_float4(acc[i][4], acc[i][5], acc[i][6], acc[i][7]);
        }
    }
}

// ---------------- finish: xn = 0.25*sum(part) + bias ; also next-layer A8 ----------------
__global__ __launch_bounds__(256) void k_gfin(const float* __restrict__ part,
                                              const float* __restrict__ bias,
                                              const float* __restrict__ WsdL,
                                              float* __restrict__ xn,
                                              float* __restrict__ A8, int M) {
    __shared__ float sW[8 * HID];
    for (int i = threadIdx.x; i < 8 * HID; i += 256) sW[i] = WsdL[i];
    __syncthreads();
    int wid = threadIdx.x >> 6, lane = threadIdx.x & 63;
    int n = blockIdx.x * 4 + wid;
    if (n >= M) return;
    size_t off = (size_t)n * HID + lane * 2;
    size_t str = (size_t)M * HID;
    float2 p0 = *(const float2*)(part + off);
    float2 p1 = *(const float2*)(part + str + off);
    float2 p2 = *(const float2*)(part + 2 * str + off);
    float2 p3 = *(const float2*)(part + 3 * str + off);
    float2 bb = *(const float2*)(bias + lane * 2);
    float2 xv;
    xv.x = 0.25f * (p0.x + p1.x + p2.x + p3.x) + bb.x;
    xv.y = 0.25f * (p0.y + p1.y + p2.y + p3.y) + bb.y;
    *(float2*)(xn + off) = xv;
    float p[8];
#pragma unroll
    for (int j = 0; j < 8; j++) {
        float v = xv.x * sW[j * HID + lane * 2] + xv.y * sW[j * HID + lane * 2 + 1];
#pragma unroll
        for (int o = 32; o; o >>= 1) v += __shfl_xor(v, o, 64);
        p[j] = v;
    }
    if (lane == 0) {
        *(float4*)(A8 + (size_t)n * 8)     = make_float4(p[0], p[1], p[2], p[3]);
        *(float4*)(A8 + (size_t)n * 8 + 4) = make_float4(p[4], p[5], p[6], p[7]);
    }
}

// ---------------- pooling: run-length local reduce (R12-proven) ----------------
#define POOL_NPB 64
__global__ __launch_bounds__(128) void k_pool(const float* __restrict__ x,
                                              const int* __restrict__ batch,
                                              float* __restrict__ g_sum,
                                              int* __restrict__ g_cnt) {
    int t = threadIdx.x;
    int n0 = blockIdx.x * POOL_NPB;
    int n1 = n0 + POOL_NPB; if (n1 > N_NODES) n1 = N_NODES;
    if (n0 >= n1) return;
    int cur = batch[n0];
    float acc = 0.f;
    int cnt = 0;
    for (int n = n0; n < n1; n++) {
        int b = batch[n];
        if (b != cur) {
            atomicAdd(&g_sum[cur * HID + t], acc);
            if (t == 0) atomicAdd(&g_cnt[cur], cnt);
            acc = 0.f; cnt = 0; cur = b;
        }
        acc += x[(size_t)n * HID + t];
        cnt++;
    }
    atomicAdd(&g_sum[cur * HID + t], acc);
    if (t == 0) atomicAdd(&g_cnt[cur], cnt);
}

// ---------------- head ----------------
__global__ __launch_bounds__(64) void k_head(const float* __restrict__ g_sum,
                                             const int* __restrict__ g_cnt,
                                             const float* __restrict__ fcW,
                                             const float* __restrict__ fcb,
                                             const float* __restrict__ outW,
                                             const float* __restrict__ outb,
                                             float* __restrict__ out) {
    int g = blockIdx.x, t = threadIdx.x;
    float inv = 1.f / fmaxf((float)g_cnt[g], 1.f);
    float val = 0.f;
    if (t < PRED_HID) {
        float dot = fcb[t];
        for (int f = 0; f < HID; f++)
            dot += (g_sum[g * HID + f] * inv) * fcW[f * PRED_HID + t];
        val = dot * outW[t];
    }
#pragma unroll
    for (int off = 32; off; off >>= 1) val += __shfl_xor(val, off, 64);
    if (t == 0) out[g] = val + outb[0];
}

extern "C" void kernel_launch(void* const* d_in, const int* in_sizes, int n_in,
                              void* d_out, int out_size, void* d_ws, size_t ws_size,
                              hipStream_t stream) {
    const float* node_feat = (const float*)d_in[0];
    const int*   edge_index = (const int*)d_in[1];
    const int*   batch     = (const int*)d_in[2];
    const float* emb_W     = (const float*)d_in[3];
    const float* emb_b     = (const float*)d_in[4];
    const float* lin_W     = (const float*)d_in[5];   // [3][128][512]
    const float* att_src   = (const float*)d_in[6];
    const float* att_dst   = (const float*)d_in[7];
    const float* conv_b    = (const float*)d_in[8];
    const float* fc_W      = (const float*)d_in[9];
    const float* fc_b      = (const float*)d_in[10];
    const float* out_W     = (const float*)d_in[11];
    const float* out_b     = (const float*)d_in[12];
    float* out = (float*)d_out;

    char* p = (char*)d_ws;
    auto alloc = [&](size_t bytes) {
        void* r = (void*)p;
        p += (bytes + 255) & ~(size_t)255;
        return r;
    };
    float* x0      = (float*)alloc((size_t)N_NODES * HID * 4);
    float* x1      = (float*)alloc((size_t)N_NODES * HID * 4);
    float* agg     = (float*)alloc((size_t)N_NODES * HHID * 4);
    float* part    = (float*)alloc((size_t)G2_KSPLIT * N_NODES * HID * 4);
    float* A8      = (float*)alloc((size_t)N_NODES * 8 * 4);
    float* Wsd     = (float*)alloc((size_t)NUM_CONV * 8 * HID * 4);
    int*   deg     = (int*)alloc((size_t)(N_NODES + 1) * 4);
    int*   row_ptr = (int*)alloc((size_t)(N_NODES + 1) * 4);
    int*   cursor  = (int*)alloc((size_t)N_NODES * 4);
    int*   csr_src = (int*)alloc((size_t)E_TOT * 4);
    float* g_sum   = (float*)alloc((size_t)N_GRAPHS * HID * 4);
    int*   g_cnt   = (int*)alloc((size_t)N_GRAPHS * 4);

    const int EB = (E_TOT + 255) / 256;
    const int NB4 = (N_NODES + 3) / 4;

    // CSR build + Wsd (topology shared across layers)
    hipMemsetAsync(deg, 0, (size_t)N_NODES * 4, stream);
    k_degwsd<<<EB, 256, 0, stream>>>(edge_index, deg, lin_W, att_src, att_dst, Wsd);
    k_scan<<<1, 1024, 0, stream>>>(deg, row_ptr, cursor);
    k_scatter<<<EB, 256, 0, stream>>>(edge_index, cursor, csr_src);

    // fused embedding + layer-0 attention projection + pooling-buffer zeroing
    k_embproj<<<NB4, 256, 0, stream>>>(node_feat, emb_W, emb_b, Wsd, x0, A8, g_sum, g_cnt);

    float* xin = x0;
    float* xout = x1;
    for (int l = 0; l < NUM_CONV; l++) {
        const float* Wl = lin_W + (size_t)l * HID * HHID;
        const float* bl = conv_b + (size_t)l * HID;
        int lnext = (l + 1 < NUM_CONV) ? l + 1 : NUM_CONV - 1;

        k_aggr<<<NB4, 256, 0, stream>>>(xin, row_ptr, csr_src, A8, agg);
        dim3 gg((N_NODES + G2_BM - 1) / G2_BM, G2_KSPLIT);
        k_gemm2<<<gg, 512, 0, stream>>>(agg, Wl, part, N_NODES);
        k_gfin<<<NB4, 256, 0, stream>>>(part, bl, Wsd + (size_t)lnext * 8 * HID,
                                        xout, A8, N_NODES);
        float* tmp = xin; xin = xout; xout = tmp;
    }

    // pooling + head (buffers pre-zeroed in k_embproj)
    k_pool<<<(N_NODES + POOL_NPB - 1) / POOL_NPB, 128, 0, stream>>>(xin, batch, g_sum, g_cnt);
    k_head<<<N_GRAPHS, 64, 0, stream>>>(g_sum, g_cnt, fc_W, fc_b,
                                        out_W, out_b, out);
}

// Round 19
// 409.421 us; speedup vs baseline: 1.0300x; 1.0300x over previous
//
#include <hip/hip_runtime.h>
#include <math.h>

#define N_NODES 20000
#define E0      320000
#define E_TOT   (E0 + N_NODES)   /* 340000: edges + self-loops */
#define N_GRAPHS 64
#define IN_DIM  39
#define HID     128
#define HEADS   4
#define HHID    (HEADS * HID)    /* 512 */
#define NUM_CONV 3
#define PRED_HID 32
#define NEG_SLOPE 0.2f

__device__ __forceinline__ int esrc(const int* __restrict__ ei, int e) {
    return e < E0 ? ei[e] : (e - E0);
}
__device__ __forceinline__ int edst(const int* __restrict__ ei, int e) {
    return e < E0 ? ei[E0 + e] : (e - E0);
}

// async global->LDS, 16B per lane; lds pointer must be wave-uniform base
__device__ __forceinline__ void gload_lds16(const void* g, void* l) {
    __builtin_amdgcn_global_load_lds(
        (const __attribute__((address_space(1))) void*)g,
        (__attribute__((address_space(3))) void*)l, 16, 0, 0);
}

// ---------------- fused: degree histogram + Wsd precompute ----------------
__global__ void k_degwsd(const int* __restrict__ ei, int* __restrict__ deg,
                         const float* __restrict__ lin_W, const float* __restrict__ attS,
                         const float* __restrict__ attD, float* __restrict__ Wsd) {
    int e = blockIdx.x * blockDim.x + threadIdx.x;
    if (e < E_TOT) atomicAdd(&deg[edst(ei, e)], 1);
    if (blockIdx.x < NUM_CONV * 8 && threadIdx.x < HID) {
        int l = blockIdx.x >> 3, j = blockIdx.x & 7, h = j & 3, k = threadIdx.x;
        const float* wr = lin_W + (size_t)l * HID * HHID + (size_t)k * HHID + h * HID;
        const float* av = ((j < 4) ? attS : attD) + ((size_t)l * HEADS + h) * HID;
        float dot = 0.f;
#pragma unroll 4
        for (int f = 0; f < HID; f++) dot += wr[f] * av[f];
        Wsd[(size_t)l * 8 * HID + j * HID + k] = dot;
    }
}

__global__ __launch_bounds__(1024) void k_scan(const int* __restrict__ deg,
                                               int* __restrict__ row_ptr,
                                               int* __restrict__ cursor) {
    __shared__ int part[1024];
    const int CHUNK = 20;
    int t = threadIdx.x;
    int base = t * CHUNK;
    int s = 0;
    for (int i = 0; i < CHUNK; i++) {
        int idx = base + i;
        if (idx < N_NODES) s += deg[idx];
    }
    part[t] = s;
    __syncthreads();
    for (int off = 1; off < 1024; off <<= 1) {
        int v = (t >= off) ? part[t - off] : 0;
        __syncthreads();
        part[t] += v;
        __syncthreads();
    }
    int run = part[t] - s;
    for (int i = 0; i < CHUNK; i++) {
        int idx = base + i;
        if (idx < N_NODES) {
            row_ptr[idx] = run;
            cursor[idx]  = run;
            run += deg[idx];
        }
    }
    if (t == 1023) row_ptr[N_NODES] = part[1023];
}

__global__ void k_scatter(const int* __restrict__ ei, int* __restrict__ cursor,
                          int* __restrict__ csr_src) {
    int e = blockIdx.x * blockDim.x + threadIdx.x;
    if (e >= E_TOT) return;
    int d = edst(ei, e);
    int pos = atomicAdd(&cursor[d], 1);
    csr_src[pos] = esrc(ei, e);
}

// ---------------- fused: embedding + layer-0 attention projection + g_sum zeroing ----------------
__global__ __launch_bounds__(256) void k_embproj(const float* __restrict__ nf,
                                                 const float* __restrict__ emb_W,
                                                 const float* __restrict__ emb_b,
                                                 const float* __restrict__ Wsd0,
                                                 float* __restrict__ x,
                                                 float* __restrict__ A8,
                                                 float* __restrict__ g_sum,
                                                 int* __restrict__ g_cnt) {
    // fold pooling-buffer zeroing in (g_sum/g_cnt untouched until k_pool)
    if (blockIdx.x < 32) g_sum[blockIdx.x * 256 + threadIdx.x] = 0.f;
    if (blockIdx.x == 32 && threadIdx.x < N_GRAPHS) g_cnt[threadIdx.x] = 0;

    __shared__ float fsh[4 * 40];
    int wid = threadIdx.x >> 6, lane = threadIdx.x & 63;
    int n = blockIdx.x * 4 + wid;
    if (n >= N_NODES) return;
    if (lane < IN_DIM) fsh[wid * 40 + lane] = nf[(size_t)n * IN_DIM + lane];
    __syncthreads();
    float2 acc = *(const float2*)(emb_b + lane * 2);
#pragma unroll
    for (int k = 0; k < IN_DIM; k++) {
        float f = fsh[wid * 40 + k];
        float2 w = *(const float2*)(emb_W + k * HID + lane * 2);
        acc.x += f * w.x; acc.y += f * w.y;
    }
    *(float2*)(x + (size_t)n * HID + lane * 2) = acc;
    float p[8];
#pragma unroll
    for (int j = 0; j < 8; j++) {
        float2 w = *(const float2*)(Wsd0 + j * HID + lane * 2);
        float v = acc.x * w.x + acc.y * w.y;
#pragma unroll
        for (int off = 32; off; off >>= 1) v += __shfl_xor(v, off, 64);
        p[j] = v;
    }
    if (lane == 0) {
        *(float4*)(A8 + (size_t)n * 8)     = make_float4(p[0], p[1], p[2], p[3]);
        *(float4*)(A8 + (size_t)n * 8 + 4) = make_float4(p[4], p[5], p[6], p[7]);
    }
}

// ---------------- aggregation with fused lane-parallel edge softmax (R12) ----------------
__global__ __launch_bounds__(256) void k_aggr(const float* __restrict__ x,
                                              const int* __restrict__ row_ptr,
                                              const int* __restrict__ csr_src,
                                              const float* __restrict__ A8,
                                              float* __restrict__ agg) {
    int wid = threadIdx.x >> 6, lane = threadIdx.x & 63;
    int n = blockIdx.x * 4 + wid;
    if (n >= N_NODES) return;
    float4 vd = *(const float4*)(A8 + (size_t)n * 8 + 4);
    int beg = row_ptr[n], end = row_ptr[n + 1];
    float a0x = 0.f, a0y = 0.f, a1x = 0.f, a1y = 0.f;
    float a2x = 0.f, a2y = 0.f, a3x = 0.f, a3y = 0.f;
    float d0 = 0.f, d1 = 0.f, d2 = 0.f, d3 = 0.f;
    size_t lo = (size_t)(lane * 2);
    int eu = lane >> 2, eh = lane & 3;
    float vdh = (eh == 0) ? vd.x : (eh == 1) ? vd.y : (eh == 2) ? vd.z : vd.w;
    int i = beg;
    for (; i + 4 <= end; i += 4) {
        int s0 = csr_src[i];
        int s1 = csr_src[i + 1];
        int s2 = csr_src[i + 2];
        int s3 = csr_src[i + 3];
        float e = 0.f;
        if (lane < 16) {
            int su = (eu == 0) ? s0 : (eu == 1) ? s1 : (eu == 2) ? s2 : s3;
            float v = A8[(size_t)su * 8 + eh] + vdh;
            v = fmaxf(v, NEG_SLOPE * v);
            e = __expf(v);
        }
        float2 xv0 = *(const float2*)(x + (size_t)s0 * HID + lo);
        float2 xv1 = *(const float2*)(x + (size_t)s1 * HID + lo);
        float2 xv2 = *(const float2*)(x + (size_t)s2 * HID + lo);
        float2 xv3 = *(const float2*)(x + (size_t)s3 * HID + lo);
        float e00 = __shfl(e, 0, 64),  e01 = __shfl(e, 1, 64),  e02 = __shfl(e, 2, 64),  e03 = __shfl(e, 3, 64);
        float e10 = __shfl(e, 4, 64),  e11 = __shfl(e, 5, 64),  e12 = __shfl(e, 6, 64),  e13 = __shfl(e, 7, 64);
        float e20 = __shfl(e, 8, 64),  e21 = __shfl(e, 9, 64),  e22 = __shfl(e, 10, 64), e23 = __shfl(e, 11, 64);
        float e30 = __shfl(e, 12, 64), e31 = __shfl(e, 13, 64), e32 = __shfl(e, 14, 64), e33 = __shfl(e, 15, 64);
        a0x += e00 * xv0.x; a0y += e00 * xv0.y;
        a1x += e01 * xv0.x; a1y += e01 * xv0.y;
        a2x += e02 * xv0.x; a2y += e02 * xv0.y;
        a3x += e03 * xv0.x; a3y += e03 * xv0.y;
        d0 += e00; d1 += e01; d2 += e02; d3 += e03;
        a0x += e10 * xv1.x; a0y += e10 * xv1.y;
        a1x += e11 * xv1.x; a1y += e11 * xv1.y;
        a2x += e12 * xv1.x; a2y += e12 * xv1.y;
        a3x += e13 * xv1.x; a3y += e13 * xv1.y;
        d0 += e10; d1 += e11; d2 += e12; d3 += e13;
        a0x += e20 * xv2.x; a0y += e20 * xv2.y;
        a1x += e21 * xv2.x; a1y += e21 * xv2.y;
        a2x += e22 * xv2.x; a2y += e22 * xv2.y;
        a3x += e23 * xv2.x; a3y += e23 * xv2.y;
        d0 += e20; d1 += e21; d2 += e22; d3 += e23;
        a0x += e30 * xv3.x; a0y += e30 * xv3.y;
        a1x += e31 * xv3.x; a1y += e31 * xv3.y;
        a2x += e32 * xv3.x; a2y += e32 * xv3.y;
        a3x += e33 * xv3.x; a3y += e33 * xv3.y;
        d0 += e30; d1 += e31; d2 += e32; d3 += e33;
    }
    for (; i < end; i++) {
        int s0 = csr_src[i];
        float4 vs = *(const float4*)(A8 + (size_t)s0 * 8);
        float2 xv0 = *(const float2*)(x + (size_t)s0 * HID + lo);
        float v0 = vs.x + vd.x; v0 = fmaxf(v0, NEG_SLOPE * v0); float e0 = __expf(v0);
        float v1 = vs.y + vd.y; v1 = fmaxf(v1, NEG_SLOPE * v1); float e1 = __expf(v1);
        float v2 = vs.z + vd.z; v2 = fmaxf(v2, NEG_SLOPE * v2); float e2 = __expf(v2);
        float v3 = vs.w + vd.w; v3 = fmaxf(v3, NEG_SLOPE * v3); float e3 = __expf(v3);
        a0x += e0 * xv0.x; a0y += e0 * xv0.y;
        a1x += e1 * xv0.x; a1y += e1 * xv0.y;
        a2x += e2 * xv0.x; a2y += e2 * xv0.y;
        a3x += e3 * xv0.x; a3y += e3 * xv0.y;
        d0 += e0; d1 += e1; d2 += e2; d3 += e3;
    }
    float i0 = 1.f / d0, i1 = 1.f / d1, i2 = 1.f / d2, i3 = 1.f / d3;
    float* ag = agg + (size_t)n * HHID;
    *(float2*)(ag + 0 * HID + lo) = make_float2(a0x * i0, a0y * i0);
    *(float2*)(ag + 1 * HID + lo) = make_float2(a1x * i1, a1y * i1);
    *(float2*)(ag + 2 * HID + lo) = make_float2(a2x * i2, a2y * i2);
    *(float2*)(ag + 3 * HID + lo) = make_float2(a3x * i3, a3y * i3);
}

// ---------------- GEMM2 split-K; B-tile staged via global_load_lds (R17 best) ----------------
#define G2_BM 64
#define G2_KSPLIT 4
__global__ __launch_bounds__(256) void k_gemm2(const float* __restrict__ agg,
                                               const float* __restrict__ W,   // [128][512]
                                               float* __restrict__ part, int M) {
    __shared__ float At[64][G2_BM];   // transposed + XOR-swizzled
    __shared__ float Bs[64 * HID];    // flat: float4 slot idx at floats [idx*4, idx*4+4)
    int tid = threadIdx.x;
    int row0 = blockIdx.x * G2_BM;
    int ks = blockIdx.y;
    int ty = tid >> 4, tx = tid & 15;
    int r0 = ty * 4, c0 = tx * 4;
    float acc[4][8] = {};

#pragma unroll
    for (int kt = 0; kt < 2; kt++) {
        int kbase = ks * 128 + kt * 64;
        __syncthreads();
        // B tile via async global->LDS (linear dest: byte offset = idx*16)
#pragma unroll
        for (int i = 0; i < 8; i++) {
            int idx = tid + i * 256;
            int kr = idx >> 5;
            int c4 = idx & 31;
            int kg = kbase + kr;
            int hd = kg >> 7, kk = kg & 127;
            const float* src = W + (size_t)kk * HHID + hd * HID + c4 * 4;
            float* ldst = Bs + ((tid & ~63) + i * 256) * 4;   // wave-uniform base
            gload_lds16(src, ldst);
        }
        // A tile: 64 rows x 64 k -> transposed + swizzled (VGPR path)
#pragma unroll
        for (int i = 0; i < 4; i++) {
            int idx = tid + i * 256;
            int r = idx >> 4;
            int c4 = idx & 15;
            int gr = row0 + r;
            float4 v = make_float4(0.f, 0.f, 0.f, 0.f);
            if (gr < M) v = *(const float4*)(agg + (size_t)gr * HHID + kbase + c4 * 4);
            int sw = (((r >> 2) ^ c4) << 2) + (r & 3);
            At[c4 * 4 + 0][sw] = v.x;
            At[c4 * 4 + 1][sw] = v.y;
            At[c4 * 4 + 2][sw] = v.z;
            At[c4 * 4 + 3][sw] = v.w;
        }
        __syncthreads();
#pragma unroll 4
        for (int k = 0; k < 64; k++) {
            float4 av = *(float4*)(&At[k][((ty ^ (k >> 2)) << 2)]);
            float4 b1 = *(float4*)(&Bs[k * HID + c0]);
            float4 b2 = *(float4*)(&Bs[k * HID + c0 + 64]);
            acc[0][0] += av.x * b1.x; acc[0][1] += av.x * b1.y; acc[0][2] += av.x * b1.z; acc[0][3] += av.x * b1.w;
            acc[0][4] += av.x * b2.x; acc[0][5] += av.x * b2.y; acc[0][6] += av.x * b2.z; acc[0][7] += av.x * b2.w;
            acc[1][0] += av.y * b1.x; acc[1][1] += av.y * b1.y; acc[1][2] += av.y * b1.z; acc[1][3] += av.y * b1.w;
            acc[1][4] += av.y * b2.x; acc[1][5] += av.y * b2.y; acc[1][6] += av.y * b2.z; acc[1][7] += av.y * b2.w;
            acc[2][0] += av.z * b1.x; acc[2][1] += av.z * b1.y; acc[2][2] += av.z * b1.z; acc[2][3] += av.z * b1.w;
            acc[2][4] += av.z * b2.x; acc[2][5] += av.z * b2.y; acc[2][6] += av.z * b2.z; acc[2][7] += av.z * b2.w;
            acc[3][0] += av.w * b1.x; acc[3][1] += av.w * b1.y; acc[3][2] += av.w * b1.z; acc[3][3] += av.w * b1.w;
            acc[3][4] += av.w * b2.x; acc[3][5] += av.w * b2.y; acc[3][6] += av.w * b2.z; acc[3][7] += av.w * b2.w;
        }
    }
    float* pb = part + (size_t)ks * M * HID;
#pragma unroll
    for (int i = 0; i < 4; i++) {
        int gr = row0 + r0 + i;
        if (gr < M) {
            *(float4*)(pb + (size_t)gr * HID + c0) =
                make_float4(acc[i][0], acc[i][1], acc[i][2], acc[i][3]);
            *(float4*)(pb + (size_t)gr * HID + c0 + 64) =
                make_float4(acc[i][4], acc[i][5], acc[i][6], acc[i][7]);
        }
    }
}

// ---------------- finish: xn = 0.25*sum(part) + bias ; also next-layer A8 ----------------
__global__ __launch_bounds__(256) void k_gfin(const float* __restrict__ part,
                                              const float* __restrict__ bias,
                                              const float* __restrict__ WsdL,
                                              float* __restrict__ xn,
                                              float* __restrict__ A8, int M) {
    __shared__ float sW[8 * HID];
    for (int i = threadIdx.x; i < 8 * HID; i += 256) sW[i] = WsdL[i];
    __syncthreads();
    int wid = threadIdx.x >> 6, lane = threadIdx.x & 63;
    int n = blockIdx.x * 4 + wid;
    if (n >= M) return;
    size_t off = (size_t)n * HID + lane * 2;
    size_t str = (size_t)M * HID;
    float2 p0 = *(const float2*)(part + off);
    float2 p1 = *(const float2*)(part + str + off);
    float2 p2 = *(const float2*)(part + 2 * str + off);
    float2 p3 = *(const float2*)(part + 3 * str + off);
    float2 bb = *(const float2*)(bias + lane * 2);
    float2 xv;
    xv.x = 0.25f * (p0.x + p1.x + p2.x + p3.x) + bb.x;
    xv.y = 0.25f * (p0.y + p1.y + p2.y + p3.y) + bb.y;
    *(float2*)(xn + off) = xv;
    float p[8];
#pragma unroll
    for (int j = 0; j < 8; j++) {
        float v = xv.x * sW[j * HID + lane * 2] + xv.y * sW[j * HID + lane * 2 + 1];
#pragma unroll
        for (int o = 32; o; o >>= 1) v += __shfl_xor(v, o, 64);
        p[j] = v;
    }
    if (lane == 0) {
        *(float4*)(A8 + (size_t)n * 8)     = make_float4(p[0], p[1], p[2], p[3]);
        *(float4*)(A8 + (size_t)n * 8 + 4) = make_float4(p[4], p[5], p[6], p[7]);
    }
}

// ---------------- pooling: run-length local reduce (R12-proven) ----------------
#define POOL_NPB 64
__global__ __launch_bounds__(128) void k_pool(const float* __restrict__ x,
                                              const int* __restrict__ batch,
                                              float* __restrict__ g_sum,
                                              int* __restrict__ g_cnt) {
    int t = threadIdx.x;
    int n0 = blockIdx.x * POOL_NPB;
    int n1 = n0 + POOL_NPB; if (n1 > N_NODES) n1 = N_NODES;
    if (n0 >= n1) return;
    int cur = batch[n0];
    float acc = 0.f;
    int cnt = 0;
    for (int n = n0; n < n1; n++) {
        int b = batch[n];
        if (b != cur) {
            atomicAdd(&g_sum[cur * HID + t], acc);
            if (t == 0) atomicAdd(&g_cnt[cur], cnt);
            acc = 0.f; cnt = 0; cur = b;
        }
        acc += x[(size_t)n * HID + t];
        cnt++;
    }
    atomicAdd(&g_sum[cur * HID + t], acc);
    if (t == 0) atomicAdd(&g_cnt[cur], cnt);
}

// ---------------- head ----------------
__global__ __launch_bounds__(64) void k_head(const float* __restrict__ g_sum,
                                             const int* __restrict__ g_cnt,
                                             const float* __restrict__ fcW,
                                             const float* __restrict__ fcb,
                                             const float* __restrict__ outW,
                                             const float* __restrict__ outb,
                                             float* __restrict__ out) {
    int g = blockIdx.x, t = threadIdx.x;
    float inv = 1.f / fmaxf((float)g_cnt[g], 1.f);
    float val = 0.f;
    if (t < PRED_HID) {
        float dot = fcb[t];
        for (int f = 0; f < HID; f++)
            dot += (g_sum[g * HID + f] * inv) * fcW[f * PRED_HID + t];
        val = dot * outW[t];
    }
#pragma unroll
    for (int off = 32; off; off >>= 1) val += __shfl_xor(val, off, 64);
    if (t == 0) out[g] = val + outb[0];
}

extern "C" void kernel_launch(void* const* d_in, const int* in_sizes, int n_in,
                              void* d_out, int out_size, void* d_ws, size_t ws_size,
                              hipStream_t stream) {
    const float* node_feat = (const float*)d_in[0];
    const int*   edge_index = (const int*)d_in[1];
    const int*   batch     = (const int*)d_in[2];
    const float* emb_W     = (const float*)d_in[3];
    const float* emb_b     = (const float*)d_in[4];
    const float* lin_W     = (const float*)d_in[5];   // [3][128][512]
    const float* att_src   = (const float*)d_in[6];
    const float* att_dst   = (const float*)d_in[7];
    const float* conv_b    = (const float*)d_in[8];
    const float* fc_W      = (const float*)d_in[9];
    const float* fc_b      = (const float*)d_in[10];
    const float* out_W     = (const float*)d_in[11];
    const float* out_b     = (const float*)d_in[12];
    float* out = (float*)d_out;

    char* p = (char*)d_ws;
    auto alloc = [&](size_t bytes) {
        void* r = (void*)p;
        p += (bytes + 255) & ~(size_t)255;
        return r;
    };
    float* x0      = (float*)alloc((size_t)N_NODES * HID * 4);
    float* x1      = (float*)alloc((size_t)N_NODES * HID * 4);
    float* agg     = (float*)alloc((size_t)N_NODES * HHID * 4);
    float* part    = (float*)alloc((size_t)G2_KSPLIT * N_NODES * HID * 4);
    float* A8      = (float*)alloc((size_t)N_NODES * 8 * 4);
    float* Wsd     = (float*)alloc((size_t)NUM_CONV * 8 * HID * 4);
    int*   deg     = (int*)alloc((size_t)(N_NODES + 1) * 4);
    int*   row_ptr = (int*)alloc((size_t)(N_NODES + 1) * 4);
    int*   cursor  = (int*)alloc((size_t)N_NODES * 4);
    int*   csr_src = (int*)alloc((size_t)E_TOT * 4);
    float* g_sum   = (float*)alloc((size_t)N_GRAPHS * HID * 4);
    int*   g_cnt   = (int*)alloc((size_t)N_GRAPHS * 4);

    const int EB = (E_TOT + 255) / 256;
    const int NB4 = (N_NODES + 3) / 4;

    // CSR build + Wsd (topology shared across layers)
    hipMemsetAsync(deg, 0, (size_t)N_NODES * 4, stream);
    k_degwsd<<<EB, 256, 0, stream>>>(edge_index, deg, lin_W, att_src, att_dst, Wsd);
    k_scan<<<1, 1024, 0, stream>>>(deg, row_ptr, cursor);
    k_scatter<<<EB, 256, 0, stream>>>(edge_index, cursor, csr_src);

    // fused embedding + layer-0 attention projection + pooling-buffer zeroing
    k_embproj<<<NB4, 256, 0, stream>>>(node_feat, emb_W, emb_b, Wsd, x0, A8, g_sum, g_cnt);

    float* xin = x0;
    float* xout = x1;
    for (int l = 0; l < NUM_CONV; l++) {
        const float* Wl = lin_W + (size_t)l * HID * HHID;
        const float* bl = conv_b + (size_t)l * HID;
        int lnext = (l + 1 < NUM_CONV) ? l + 1 : NUM_CONV - 1;

        k_aggr<<<NB4, 256, 0, stream>>>(xin, row_ptr, csr_src, A8, agg);
        dim3 gg((N_NODES + G2_BM - 1) / G2_BM, G2_KSPLIT);
        k_gemm2<<<gg, 256, 0, stream>>>(agg, Wl, part, N_NODES);
        k_gfin<<<NB4, 256, 0, stream>>>(part, bl, Wsd + (size_t)lnext * 8 * HID,
                                        xout, A8, N_NODES);
        float* tmp = xin; xin = xout; xout = tmp;
    }

    // pooling + head (buffers pre-zeroed in k_embproj)
    k_pool<<<(N_NODES + POOL_NPB - 1) / POOL_NPB, 128, 0, stream>>>(xin, batch, g_sum, g_cnt);
    k_head<<<N_GRAPHS, 64, 0, stream>>>(g_sum, g_cnt, fc_W, fc_b,
                                        out_W, out_b, out);
}